// Round 9
// baseline (2374.720 us; speedup 1.0000x reference)
//
#include <hip/hip_runtime.h>
#include <math.h>

// ---------------------------------------------------------------------------
// Dictionary_56212531970303 : FISTA dictionary forward on MI355X, fp32.
// Setup: prep1, k_PP, k_impulse, k_dft, atoms1 (+transposed copy),
//        k_M (16-block Gram), k_fin (M^2 + power + finalize).
// Loop (20 iters):
//   kA  — 512-thr blocks; og=readfirstlane(tid>>8) so X/atomsT rows are
//         wave-uniform -> SMEM s_load operands (no LDS staging of weights);
//   kB1 — 256-thr blocks, 4 px/thread, 512 blocks = 8 waves/CU (round-5 rule);
//   kB2 — image update + residual partials (flag reduced in next iter's blocks).
// Iter 1 templated FIRST; iter 20 writes directly into d_out.
// NOTE: every "if (tid<N)" with N>blockDim must be a grid-stride loop —
// round-2/3 regression: `if(tid<289)` under 256 threads left pi[256..288]
// unwritten (deterministic absmax 0.134).
// ---------------------------------------------------------------------------

#define NB 4
#define NCH 64
#define NPIX 16384              // 128*128
#define NCOEF (NB*NCH*NPIX)     // 4194304
#define NIMG  (NB*NPIX)         // 65536
#define TOLV 1e-4f

#define SC_BETA 0
#define SC_L    1
#define SC_G    4
#define SC_G2   5
#define SC_LPK2 6

// ---------------------------------------------------------------------------
// prep1: one block. bjorck via 8x8 gram-iteration; writes gram + pf + scalars.
__global__ __launch_bounds__(256) void k_prep1(const float* __restrict__ fatoms,
    const float* __restrict__ beta_p,
    float* __restrict__ gram_g, float* __restrict__ pf_g,
    float* __restrict__ scalars)
{
    __shared__ float sW[648], sWf[648];
    __shared__ float sG[64], sP[64], sF[64], sT[64], sTmp[64];
    __shared__ float sGr[6561];
    __shared__ float rs[81];
    __shared__ float sSig;
    int tid = threadIdx.x;
    if (tid==0){ float b=beta_p[0]; scalars[SC_BETA]=(b>0.f)?b:0.f;
                 ((unsigned*)scalars)[SC_LPK2]=0u; }
    for (int e=tid; e<648; e+=256) sW[e]=fatoms[e];
    __syncthreads();
    // G0 = W W^T (8x8)
    if (tid<64){ int r=tid>>3, s=tid&7; float a=0.f;
        for (int k=0;k<81;++k) a=fmaf(sW[r*81+k],sW[s*81+k],a); sG[tid]=a; }
    __syncthreads();
    // power iteration on G0 -> sigma = ||W||_2
    if (tid<64){
        int r8 = tid&7;
        float v = 1.f;
        for (int it=0; it<128; ++it){
            float nv=0.f;
            #pragma unroll
            for (int j=0;j<8;++j) nv = fmaf(sG[r8*8+j], __shfl(v,j,8), nv);
            float m = fabsf(nv);
            m = fmaxf(m, __shfl_xor(m,1,8));
            m = fmaxf(m, __shfl_xor(m,2,8));
            m = fmaxf(m, __shfl_xor(m,4,8));
            v = nv/m;
        }
        float wv=0.f;
        #pragma unroll
        for (int j=0;j<8;++j) wv = fmaf(sG[r8*8+j], __shfl(v,j,8), wv);
        float num=v*wv, den=v*v;
        num += __shfl_xor(num,1,8); num += __shfl_xor(num,2,8); num += __shfl_xor(num,4,8);
        den += __shfl_xor(den,1,8); den += __shfl_xor(den,2,8); den += __shfl_xor(den,4,8);
        if (tid==0) sSig = sqrtf(num/den);
    }
    __syncthreads();
    float inv_s = 1.f/sSig;
    for (int e=tid; e<648; e+=256) sW[e]*=inv_s;
    if (tid<64){ sG[tid]*=inv_s*inv_s; sP[tid]=((tid>>3)==(tid&7))?1.f:0.f; }
    __syncthreads();
    // bjorck on the 8x8: F=1.5I-0.5G; P=F P; G=F G F.  15 iters.
    for (int it=0; it<15; ++it){
        if (tid<64) sF[tid] = (((tid>>3)==(tid&7))?1.5f:0.f) - 0.5f*sG[tid];
        __syncthreads();
        if (tid<64){ int r=tid>>3, c=tid&7; float ap=0.f, ag=0.f;
            #pragma unroll
            for (int k=0;k<8;++k){ float f=sF[r*8+k]; ap=fmaf(f,sP[k*8+c],ap); ag=fmaf(f,sG[k*8+c],ag); }
            sTmp[tid]=ap; sT[tid]=ag; }
        __syncthreads();
        if (tid<64){ int r=tid>>3, c=tid&7; float g2=0.f;
            #pragma unroll
            for (int k=0;k<8;++k) g2=fmaf(sT[r*8+k],sF[k*8+c],g2);
            sG[tid]=g2; sP[tid]=sTmp[tid]; }
        __syncthreads();
    }
    // Wf = P @ Ws  (8x81)
    for (int e=tid; e<648; e+=256){ int r=e/81, j=e%81; float a=0.f;
        #pragma unroll
        for (int k=0;k<8;++k) a=fmaf(sP[r*8+k], sW[k*81+j], a);
        sWf[e]=a; }
    __syncthreads();
    // gram = Wf^T Wf (81x81, K=8)
    for (int e=tid; e<6561; e+=256){ int i=e/81, j=e%81; float a=0.f;
        #pragma unroll
        for (int r=0;r<8;++r) a=fmaf(sWf[r*81+i],sWf[r*81+j],a);
        sGr[e]=a; gram_g[e]=a; }
    __syncthreads();
    if (tid<81){ float s=0.f; for (int k=0;k<81;++k) s+=sGr[tid*81+k]; rs[tid]=(1.f-s)/81.f; }
    __syncthreads();
    // pf = (I - gram) - rowmean_j  -> global
    for (int e=tid; e<6561; e+=256){ int i=e/81, j=e%81;
        pf_g[e] = ((i==j)?1.f:0.f) - sGr[e] - rs[j]; }
}

// PP = pf^T pf (81x81), pf staged in LDS. 26 blocks x 256 thr.
__global__ __launch_bounds__(256) void k_PP(const float* __restrict__ pf, float* __restrict__ PP)
{
    __shared__ float spf[6561];
    for (int e=threadIdx.x; e<6561; e+=256) spf[e]=pf[e];
    __syncthreads();
    int e = blockIdx.x*256 + threadIdx.x;
    if (e>=6561) return;
    int al=e/81, be=e%81; float a=0.f;
    for (int c=0;c<81;++c) a=fmaf(spf[c*81+al], spf[c*81+be], a);
    PP[e]=a;
}

// proj_impulse (17x17) via PP lookups. One block, 320 thr (guard: t<289).
__global__ void k_impulse(const float* __restrict__ PP, float* __restrict__ pi)
{
    int t = threadIdx.x;
    if (t>=289) return;
    int h=t/17, w=t%17;
    float acc=0.f;
    for (int p=0;p<9;++p){
        int i2=(h+p-4+17)%17;
        if (i2<4||i2>12) continue;
        for (int q=0;q<9;++q){
            int j2=(w+q-4+17)%17;
            if (j2<4||j2>12) continue;
            int al=(12-i2)*9+(12-j2);
            int be=(8-p)*9+(8-q);
            acc += PP[al*81+be];
        }
    }
    pi[t]=acc;
}

// |FFT2(pi zero-padded to 128x128)|^2 max. 256 blocks x 64 thr (1 wave).
__global__ __launch_bounds__(64) void k_dft(const float* __restrict__ pi, float* __restrict__ scalars)
{
    __shared__ float spi[289], ct[128], st[128];
    int tid=threadIdx.x; int gid=blockIdx.x*64+tid;
    for (int e=tid; e<289; e+=64) spi[e]=pi[e];
    for (int e=tid; e<128; e+=64){ float ang=(float)e*(6.28318530717958647692f/128.f);
                  ct[e]=cosf(ang); st[e]=sinf(ang); }
    __syncthreads();
    int u=gid>>7, v=gid&127;
    float re=0.f, im=0.f;
    for (int i=0;i<17;++i){
        int ku=(u*i)&127;
        const float* prow=spi+i*17;
        for (int j=0;j<17;++j){
            int k=(ku+v*j)&127;
            float x=prow[j];
            re=fmaf(x,ct[k],re); im=fmaf(x,st[k],im);
        }
    }
    float m2=re*re+im*im;
    #pragma unroll
    for (int d=32; d; d>>=1) m2=fmaxf(m2, __shfl_down(m2,d));
    if (tid==0) atomicMax(((unsigned*)scalars)+SC_LPK2, __float_as_uint(m2));
}

// per-atom: center, subtract af@gram, row-normalize. Writes af_rn AND af_rnT.
__global__ __launch_bounds__(128) void k_atoms1(const float* __restrict__ atoms_in,
    const float* __restrict__ gram, float* __restrict__ af_rn, float* __restrict__ af_rnT)
{
    int a=blockIdx.x, tid=threadIdx.x;
    __shared__ float a0[81], a1[81], rbuf[128];
    float v = (tid<81)? atoms_in[a*81+tid] : 0.f;
    rbuf[tid]=v; __syncthreads();
    for (int off=64; off; off>>=1){ if (tid<off) rbuf[tid]+=rbuf[tid+off]; __syncthreads(); }
    float mean = rbuf[0]/81.f;
    __syncthreads();
    if (tid<81) a0[tid]=v-mean;
    __syncthreads();
    float w=0.f;
    if (tid<81){ float dot=0.f;
        for (int k=0;k<81;++k) dot=fmaf(a0[k], gram[k*81+tid], dot);
        w=a0[tid]-dot; a1[tid]=w; }
    rbuf[tid]=(tid<81)? w*w : 0.f;
    __syncthreads();
    for (int off=64; off; off>>=1){ if (tid<off) rbuf[tid]+=rbuf[tid+off]; __syncthreads(); }
    float inv = 1.f/sqrtf(rbuf[0]);
    if (tid<81){ float r=a1[tid]*inv; af_rn[a*81+tid]=r; af_rnT[tid*64+a]=r; }
}

// M = af_rn af_rn^T. 16 blocks x 256. Row i uniform per wave -> s_load;
// af_rnT[k*64+j] coalesced per lane.
__global__ __launch_bounds__(256) void k_M(const float* __restrict__ af_rn,
    const float* __restrict__ af_rnT, float* __restrict__ M)
{
    int e=blockIdx.x*256+threadIdx.x;
    int i=e>>6, j=e&63;
    float a=0.f;
    for (int k=0;k<81;++k) a=fmaf(af_rn[i*81+k], af_rnT[(k<<6)+j], a);
    M[e]=a;
}

// k_fin: one block. Stage M, A=M^2 (padded float4 rows), power 48 on A,
// Rayleigh with M, finalize atoms_f / atomsT / Xmat / scalars.
__global__ __launch_bounds__(256) void k_fin(const float* __restrict__ Mg,
    const float* __restrict__ af_rn, float* __restrict__ scalars,
    float* __restrict__ atoms_f, float* __restrict__ atomsT, float* __restrict__ Xmat)
{
    __shared__ __align__(16) float sM [64*68];   // rows padded 64->68
    __shared__ __align__(16) float sA [64*68];
    __shared__ float sGc[2];
    int tid=threadIdx.x;
    for (int e=tid; e<4096; e+=256) sM[(e>>6)*68+(e&63)]=Mg[e];
    for (int e=tid; e<64*68; e+=256){ if ((e%68)>=64) sM[e]=0.f; }
    __syncthreads();
    // A = M^2 (M symmetric: col j == row j)
    for (int e=tid; e<4096; e+=256){
        int i=e>>6, j=e&63;
        const float4* ri = reinterpret_cast<const float4*>(sM + i*68);
        const float4* rj = reinterpret_cast<const float4*>(sM + j*68);
        float a0=0.f,a1=0.f,a2=0.f,a3=0.f;
        #pragma unroll
        for (int k=0;k<16;++k){
            float4 x=ri[k], y=rj[k];
            a0=fmaf(x.x,y.x,a0); a1=fmaf(x.y,y.y,a1);
            a2=fmaf(x.z,y.z,a2); a3=fmaf(x.w,y.w,a3);
        }
        sA[i*68+j]=(a0+a1)+(a2+a3);
    }
    __syncthreads();
    if (tid<64){
        float m[64];
        #pragma unroll
        for (int j=0;j<64;++j) m[j]=sA[tid*68+j];
        float v = 1.0f + 0.01f*(float)tid;
        for (int it=0; it<48; ++it){
            float a0=0.f,a1=0.f,a2=0.f,a3=0.f;
            #pragma unroll
            for (int j=0;j<64;j+=4){
                a0=fmaf(m[j+0], __shfl(v,j+0), a0);
                a1=fmaf(m[j+1], __shfl(v,j+1), a1);
                a2=fmaf(m[j+2], __shfl(v,j+2), a2);
                a3=fmaf(m[j+3], __shfl(v,j+3), a3);
            }
            float nv=(a0+a1)+(a2+a3);
            float mx=fabsf(nv);
            #pragma unroll
            for (int d=1; d<64; d<<=1) mx=fmaxf(mx, __shfl_xor(mx,d));
            v=nv/mx;
        }
        float w0=0.f,w1=0.f,w2=0.f,w3=0.f;
        #pragma unroll
        for (int j=0;j<64;j+=4){
            w0=fmaf(sM[tid*68+j+0], __shfl(v,j+0), w0);
            w1=fmaf(sM[tid*68+j+1], __shfl(v,j+1), w1);
            w2=fmaf(sM[tid*68+j+2], __shfl(v,j+2), w2);
            w3=fmaf(sM[tid*68+j+3], __shfl(v,j+3), w3);
        }
        float wv=(w0+w1)+(w2+w3);
        float num=v*wv, den=v*v;
        #pragma unroll
        for (int d=1; d<64; d<<=1){ num+=__shfl_xor(num,d); den+=__shfl_xor(den,d); }
        if (tid==0){
            float sig = sqrtf(num/den);
            float b = scalars[SC_BETA];
            float s = sqrtf(0.99f/fmaxf(b,0.1f));
            float g = s/sig;
            scalars[SC_G]=g; scalars[SC_G2]=g*g;
            float lpk = sqrtf(__uint_as_float(((unsigned*)scalars)[SC_LPK2]));
            scalars[SC_L] = 1.01f*b*lpk;
            sGc[0]=g; sGc[1]=g*g;
        }
    }
    __syncthreads();
    float g=sGc[0], g2=sGc[1];
    for (int idx=tid; idx<5184; idx+=256){
        int a=idx/81, pq=idx-a*81;
        float v=g*af_rn[idx];
        atoms_f[idx]=v;
        atomsT[pq*64+a]=v;
    }
    for (int e=tid; e<4096; e+=256) Xmat[e]=g2*sM[(e>>6)*68+(e&63)];
}

// ---------------------------------------------------------------------------
// kA: coefficient update. grid (row-pair, batch), 512 threads; og =
// readfirstlane(tid>>8) -> X/atomsT row addresses are wave-uniform ->
// compiler emits scalar (SMEM) loads; only simg lives in LDS.
template<bool FIRST>
__global__ __launch_bounds__(512) void kA(const float* __restrict__ c_in,
    const float* __restrict__ nc_in, const float* __restrict__ nimg,
    const float* __restrict__ Xmat, const float* __restrict__ atomsT,
    const float* __restrict__ scalars, const float* __restrict__ lmbda_p,
    const float* __restrict__ red_in,
    float* __restrict__ c_out, float* __restrict__ nc_out, float mom)
{
    int b=blockIdx.y, rp=blockIdx.x;
    int tid=threadIdx.x;
    int og = __builtin_amdgcn_readfirstlane(tid>>8);  // wave-uniform half
    int lid = tid&255;
    int ty=lid>>7, w=lid&127;
    int h0=rp*2;
    __shared__ float simg[10*128];
    __shared__ float sAct;
    if (FIRST){ if (tid==0) sAct=1.f; }
    else if (tid<64){
        float sd=red_in[(b<<7)+(tid<<1)], si=red_in[(b<<7)+(tid<<1)+1];
        #pragma unroll
        for (int off=32; off; off>>=1){ sd+=__shfl_down(sd,off); si+=__shfl_down(si,off); }
        if (tid==0) sAct = (sd > TOLV*TOLV*si) ? 1.f : 0.f;
    }
    for (int e=tid; e<1280; e+=512)
        simg[e]=nimg[b*NPIX + (((h0-4+(e>>7))&127)<<7) + (e&127)];
    __syncthreads();
    int pix=((h0+ty)<<7)+w;
    const float* cp  = c_in  + b*NCH*NPIX + pix;
    const float* ncp = nc_in + b*NCH*NPIX + pix;
    const float* Xo  = Xmat   + og*32;   // wave-uniform row bases
    const float* Ao  = atomsT + og*32;
    float acc[32];
    #pragma unroll
    for (int o=0;o<32;++o) acc[o]=0.f;
    if (!FIRST){
        for (int c=0;c<64;++c){
            float ncv=ncp[c*NPIX], cv=cp[c*NPIX];
            float t=fmaf(mom, ncv-cv, ncv);
            const float* Xr = Xo + (c<<6);      // uniform -> s_load
            #pragma unroll
            for (int i=0;i<32;++i) acc[i]=fmaf(Xr[i], t, acc[i]);
        }
    }
    for (int p=0;p<9;++p){
        const float* srow = simg + (ty+p)*128;
        #pragma unroll 3
        for (int q=0;q<9;++q){
            float wv = -srow[(w+q-4)&127];
            const float* Ar = Ao + ((p*9+q)<<6);  // uniform -> s_load
            #pragma unroll
            for (int i=0;i<32;++i) acc[i]=fmaf(Ar[i], wv, acc[i]);
        }
    }
    float beta=scalars[SC_BETA], lmb=lmbda_p[0];
    bool act = (sAct!=0.f);
    int co = og*32;
    const float* cpo  = cp  + co*NPIX;
    const float* ncpo = ncp + co*NPIX;
    float* cop  = c_out  + b*NCH*NPIX + co*NPIX + pix;
    float* ncop = nc_out + b*NCH*NPIX + co*NPIX + pix;
    #pragma unroll
    for (int o=0;o<32;++o){
        float ncv, cv, t;
        if (FIRST){ ncv=0.f; cv=0.f; t=0.f; }
        else { ncv=ncpo[o*NPIX]; cv=cpo[o*NPIX]; t=fmaf(mom, ncv-cv, ncv); }
        float u=fmaf(-beta, acc[o], t);
        float au=fabsf(u)-lmb;
        u = (au>0.f)? copysignf(au,u) : 0.f;
        ncop[o*NPIX] = act? u : ncv;
        cop[o*NPIX]  = act? ncv : cv;
    }
}

// kB1: dict_pred partials over 8-channel groups. 256 thr, 4 px/thread,
// grid (16,8,4) = 512 blocks -> 8 waves/CU (round-5 occupancy rule).
__global__ __launch_bounds__(256) void kB1(const float* __restrict__ nc2,
    const float* __restrict__ atoms_f, float* __restrict__ part)
{
    int b=blockIdx.z, g=blockIdx.y, pb=blockIdx.x;
    int t=threadIdx.x;
    int row = pb*8 + (t>>5);
    int cb  = (t&31)*4;
    const float* src = nc2 + (b*NCH + g*8)*NPIX;
    float acc[4]={0.f,0.f,0.f,0.f};
    for (int c=0;c<8;++c){
        const float* chan = src + c*NPIX;
        const float* arow = atoms_f + (g*8+c)*81;   // uniform -> s_load
        for (int p=0;p<9;++p){
            int r=(row+4-p)&127;
            const float* rp_ = chan + (r<<7);
            float in12[12];
            #pragma unroll
            for (int k4=0;k4<3;++k4){
                int col=(cb-4+(k4<<2))&127;
                const float4 vv = *reinterpret_cast<const float4*>(rp_+col);
                in12[(k4<<2)+0]=vv.x; in12[(k4<<2)+1]=vv.y;
                in12[(k4<<2)+2]=vv.z; in12[(k4<<2)+3]=vv.w;
            }
            #pragma unroll
            for (int q=0;q<9;++q){
                float a = arow[p*9+q];
                #pragma unroll
                for (int k=0;k<4;++k) acc[k]=fmaf(in12[k+8-q], a, acc[k]);
            }
        }
    }
    float* dst = part + (g*NB+b)*NPIX + (row<<7) + cb;
    #pragma unroll
    for (int k=0;k<4;++k) dst[k]=acc[k];
}

// kB2: image update + residual block partials (+ in-block active flag)
template<bool FIRST>
__global__ __launch_bounds__(256) void kB2(const float* __restrict__ img,
    const float* __restrict__ nimg, const float* __restrict__ y,
    const float* __restrict__ part, const float* __restrict__ pi,
    const float* __restrict__ scalars, const float* __restrict__ red_in,
    float* __restrict__ img_out, float* __restrict__ nimg_out,
    float* __restrict__ red_out, float mom)
{
    int b=blockIdx.y, rp=blockIdx.x;
    int tid=threadIdx.x, ty=tid>>7, w=tid&127;
    int h0=rp*2;
    __shared__ float sti[18*128];
    __shared__ float spi[289];
    __shared__ float rsd[4], rsi[4];
    __shared__ float sAct;
    if (FIRST){ if (tid==0) sAct=1.f; }
    else if (tid<64){
        float sd=red_in[(b<<7)+(tid<<1)], si=red_in[(b<<7)+(tid<<1)+1];
        #pragma unroll
        for (int off=32; off; off>>=1){ sd+=__shfl_down(sd,off); si+=__shfl_down(si,off); }
        if (tid==0) sAct = (sd > TOLV*TOLV*si) ? 1.f : 0.f;
    }
    const float* ib  = img  + b*NPIX;
    const float* nib = nimg + b*NPIX;
    for (int e=tid; e<2304; e+=256){
        int r=e>>7, cc=e&127;
        int idx=(((h0-8+r)&127)<<7)+cc;
        float nv=nib[idx], v=ib[idx];
        sti[e]=fmaf(mom, nv-v, nv);
    }
    for (int e=tid; e<289; e+=256) spi[e]=pi[e];
    __syncthreads();
    float sp=0.f;
    for (int p=0;p<17;++p){
        const float* srow = sti + (ty+p)*128;
        const float* pr = spi + p*17;
        #pragma unroll
        for (int q=0;q<17;++q) sp=fmaf(srow[(w+q-8)&127], pr[q], sp);
    }
    int pix=((h0+ty)<<7)+w;
    float dp=0.f;
    #pragma unroll
    for (int g=0; g<8; ++g) dp += part[(g*NB+b)*NPIX + pix];
    float ti = sti[(ty+8)*128 + w];
    float beta=scalars[SC_BETA], L=scalars[SC_L];
    float yv=y[b*NPIX+pix];
    float upd = ti - (ti - yv + beta*(sp - dp))/L;
    bool act = (sAct!=0.f);
    float iv=ib[pix], niv=nib[pix];
    float i2 = act? niv : iv;
    float ni2 = act? upd : niv;
    img_out[b*NPIX+pix]=i2;
    nimg_out[b*NPIX+pix]=ni2;
    float d=i2-ni2;
    float sd=d*d, si=i2*i2;
    #pragma unroll
    for (int off=32; off; off>>=1){ sd+=__shfl_down(sd,off); si+=__shfl_down(si,off); }
    if ((tid&63)==0){ rsd[tid>>6]=sd; rsi[tid>>6]=si; }
    __syncthreads();
    if (tid==0){
        float a=rsd[0]+rsd[1]+rsd[2]+rsd[3];
        float c2=rsi[0]+rsi[1]+rsi[2]+rsi[3];
        red_out[(b<<7)+(rp<<1)+0]=a;
        red_out[(b<<7)+(rp<<1)+1]=c2;
    }
}

// ---------------------------------------------------------------------------
extern "C" void kernel_launch(void* const* d_in, const int* in_sizes, int n_in,
                              void* d_out, int out_size, void* d_ws, size_t ws_size,
                              hipStream_t stream)
{
    const float* y        = (const float*)d_in[0];
    const float* atoms_p  = (const float*)d_in[1];
    const float* fatoms_p = (const float*)d_in[2];
    const float* beta_p   = (const float*)d_in[3];
    const float* lmbda_p  = (const float*)d_in[4];
    float* out = (float*)d_out;
    float* w = (float*)d_ws;

    size_t off=0;
    float* cb[2];  cb[0]=w+off;  off+=NCOEF; cb[1]=w+off;  off+=NCOEF;
    float* ncb[2]; ncb[0]=w+off; off+=NCOEF; ncb[1]=w+off; off+=NCOEF;
    float* ib[2];  ib[0]=w+off;  off+=NIMG;  ib[1]=w+off;  off+=NIMG;
    float* nib[2]; nib[0]=w+off; off+=NIMG;  nib[1]=w+off; off+=NIMG;
    float* part=w+off;    off+=8*NIMG;
    float* red[2]; red[0]=w+off; off+=512; red[1]=w+off; off+=512;
    float* gram=w+off;    off+=6561;
    float* pf=w+off;      off+=6561;
    float* PP=w+off;      off+=6561;
    float* pi=w+off;      off+=512;
    float* af_rn=w+off;   off+=5184;
    float* af_rnT=w+off;  off+=5184;
    float* Mmat=w+off;    off+=4096;
    float* atoms_f=w+off; off+=5184;
    float* atomsT=w+off;  off+=5184;
    float* Xmat=w+off;    off+=4096;
    float* scalars=w+off; off+=32;

    k_prep1<<<dim3(1),dim3(256),0,stream>>>(fatoms_p, beta_p, gram, pf, scalars);
    k_PP<<<dim3(26),dim3(256),0,stream>>>(pf, PP);
    k_impulse<<<dim3(1),dim3(320),0,stream>>>(PP, pi);
    k_dft<<<dim3(256),dim3(64),0,stream>>>(pi, scalars);
    k_atoms1<<<dim3(64),dim3(128),0,stream>>>(atoms_p, gram, af_rn, af_rnT);
    k_M<<<dim3(16),dim3(256),0,stream>>>(af_rn, af_rnT, Mmat);
    k_fin<<<dim3(1),dim3(256),0,stream>>>(Mmat, af_rn, scalars, atoms_f, atomsT, Xmat);

    int p=0;
    for (int k=1; k<=20; ++k){
        float mom = (float)(k-1)/(float)(k+2);
        const float* rin = red[(k-1)&1];
        float* rout = red[k&1];
        const float* img_i  = (k==1)? y : ib[p];
        const float* nimg_i = (k==1)? y : nib[p];
        float* nc_t  = (k==20)? (out+NIMG) : ncb[p^1];
        float* nimg_t= (k==20)? out : nib[p^1];
        if (k==1){
            kA<true><<<dim3(64,4),dim3(512),0,stream>>>(cb[p],ncb[p],nimg_i,Xmat,atomsT,
                scalars,lmbda_p,rin, cb[p^1],nc_t,mom);
        } else {
            kA<false><<<dim3(64,4),dim3(512),0,stream>>>(cb[p],ncb[p],nimg_i,Xmat,atomsT,
                scalars,lmbda_p,rin, cb[p^1],nc_t,mom);
        }
        kB1<<<dim3(16,8,4),dim3(256),0,stream>>>(nc_t, atoms_f, part);
        if (k==1){
            kB2<true><<<dim3(64,4),dim3(256),0,stream>>>(img_i,nimg_i,y,part,pi,scalars,rin,
                ib[p^1],nimg_t,rout,mom);
        } else {
            kB2<false><<<dim3(64,4),dim3(256),0,stream>>>(img_i,nimg_i,y,part,pi,scalars,rin,
                ib[p^1],nimg_t,rout,mom);
        }
        p^=1;
    }
}

// Round 10
// 1609.564 us; speedup vs baseline: 1.4754x; 1.4754x over previous
//
#include <hip/hip_runtime.h>
#include <math.h>

// ---------------------------------------------------------------------------
// Dictionary_56212531970303 : FISTA dictionary forward on MI355X, fp32.
// Setup: prep1, k_PP, k_impulse, k_dft, atoms1 (+af_rnT), k_M, k_fin.
// Loop (20 iters):
//   kA  — 512-thr blocks, og halves merged (round-8 proven: one c/nc HBM
//         fetch), weights LDS-staged;
//   kB1 — dict_pred partials, CHANNEL-split: 16 cgroups x 4 ch, 128 thr,
//         8 px/thread (keeps 18 fma per float4 load — round-9 lesson:
//         splitting pixels amplifies loads; split channels instead);
//   kB2 — image update + residual partials (sums 16 partial groups).
// Iter 1 templated FIRST; iter 20 writes directly into d_out.
// NOTE: every "if (tid<N)" with N>blockDim must be a grid-stride loop —
// round-2/3 regression: `if(tid<289)` under 256 threads left pi[256..288]
// unwritten (deterministic absmax 0.134).
// ---------------------------------------------------------------------------

#define NB 4
#define NCH 64
#define NPIX 16384              // 128*128
#define NCOEF (NB*NCH*NPIX)     // 4194304
#define NIMG  (NB*NPIX)         // 65536
#define NPG 16                  // partial channel-groups (4 ch each)
#define TOLV 1e-4f

#define SC_BETA 0
#define SC_L    1
#define SC_G    4
#define SC_G2   5
#define SC_LPK2 6

// ---------------------------------------------------------------------------
// prep1: one block. bjorck via 8x8 gram-iteration; writes gram + pf + scalars.
__global__ __launch_bounds__(256) void k_prep1(const float* __restrict__ fatoms,
    const float* __restrict__ beta_p,
    float* __restrict__ gram_g, float* __restrict__ pf_g,
    float* __restrict__ scalars)
{
    __shared__ float sW[648], sWf[648];
    __shared__ float sG[64], sP[64], sF[64], sT[64], sTmp[64];
    __shared__ float sGr[6561];
    __shared__ float rs[81];
    __shared__ float sSig;
    int tid = threadIdx.x;
    if (tid==0){ float b=beta_p[0]; scalars[SC_BETA]=(b>0.f)?b:0.f;
                 ((unsigned*)scalars)[SC_LPK2]=0u; }
    for (int e=tid; e<648; e+=256) sW[e]=fatoms[e];
    __syncthreads();
    if (tid<64){ int r=tid>>3, s=tid&7; float a=0.f;
        for (int k=0;k<81;++k) a=fmaf(sW[r*81+k],sW[s*81+k],a); sG[tid]=a; }
    __syncthreads();
    if (tid<64){
        int r8 = tid&7;
        float v = 1.f;
        for (int it=0; it<128; ++it){
            float nv=0.f;
            #pragma unroll
            for (int j=0;j<8;++j) nv = fmaf(sG[r8*8+j], __shfl(v,j,8), nv);
            float m = fabsf(nv);
            m = fmaxf(m, __shfl_xor(m,1,8));
            m = fmaxf(m, __shfl_xor(m,2,8));
            m = fmaxf(m, __shfl_xor(m,4,8));
            v = nv/m;
        }
        float wv=0.f;
        #pragma unroll
        for (int j=0;j<8;++j) wv = fmaf(sG[r8*8+j], __shfl(v,j,8), wv);
        float num=v*wv, den=v*v;
        num += __shfl_xor(num,1,8); num += __shfl_xor(num,2,8); num += __shfl_xor(num,4,8);
        den += __shfl_xor(den,1,8); den += __shfl_xor(den,2,8); den += __shfl_xor(den,4,8);
        if (tid==0) sSig = sqrtf(num/den);
    }
    __syncthreads();
    float inv_s = 1.f/sSig;
    for (int e=tid; e<648; e+=256) sW[e]*=inv_s;
    if (tid<64){ sG[tid]*=inv_s*inv_s; sP[tid]=((tid>>3)==(tid&7))?1.f:0.f; }
    __syncthreads();
    for (int it=0; it<15; ++it){
        if (tid<64) sF[tid] = (((tid>>3)==(tid&7))?1.5f:0.f) - 0.5f*sG[tid];
        __syncthreads();
        if (tid<64){ int r=tid>>3, c=tid&7; float ap=0.f, ag=0.f;
            #pragma unroll
            for (int k=0;k<8;++k){ float f=sF[r*8+k]; ap=fmaf(f,sP[k*8+c],ap); ag=fmaf(f,sG[k*8+c],ag); }
            sTmp[tid]=ap; sT[tid]=ag; }
        __syncthreads();
        if (tid<64){ int r=tid>>3, c=tid&7; float g2=0.f;
            #pragma unroll
            for (int k=0;k<8;++k) g2=fmaf(sT[r*8+k],sF[k*8+c],g2);
            sG[tid]=g2; sP[tid]=sTmp[tid]; }
        __syncthreads();
    }
    for (int e=tid; e<648; e+=256){ int r=e/81, j=e%81; float a=0.f;
        #pragma unroll
        for (int k=0;k<8;++k) a=fmaf(sP[r*8+k], sW[k*81+j], a);
        sWf[e]=a; }
    __syncthreads();
    for (int e=tid; e<6561; e+=256){ int i=e/81, j=e%81; float a=0.f;
        #pragma unroll
        for (int r=0;r<8;++r) a=fmaf(sWf[r*81+i],sWf[r*81+j],a);
        sGr[e]=a; gram_g[e]=a; }
    __syncthreads();
    if (tid<81){ float s=0.f; for (int k=0;k<81;++k) s+=sGr[tid*81+k]; rs[tid]=(1.f-s)/81.f; }
    __syncthreads();
    for (int e=tid; e<6561; e+=256){ int i=e/81, j=e%81;
        pf_g[e] = ((i==j)?1.f:0.f) - sGr[e] - rs[j]; }
}

// PP = pf^T pf (81x81), pf staged in LDS. 26 blocks x 256 thr.
__global__ __launch_bounds__(256) void k_PP(const float* __restrict__ pf, float* __restrict__ PP)
{
    __shared__ float spf[6561];
    for (int e=threadIdx.x; e<6561; e+=256) spf[e]=pf[e];
    __syncthreads();
    int e = blockIdx.x*256 + threadIdx.x;
    if (e>=6561) return;
    int al=e/81, be=e%81; float a=0.f;
    for (int c=0;c<81;++c) a=fmaf(spf[c*81+al], spf[c*81+be], a);
    PP[e]=a;
}

// proj_impulse (17x17) via PP lookups. One block, 320 thr (guard: t<289).
__global__ void k_impulse(const float* __restrict__ PP, float* __restrict__ pi)
{
    int t = threadIdx.x;
    if (t>=289) return;
    int h=t/17, w=t%17;
    float acc=0.f;
    for (int p=0;p<9;++p){
        int i2=(h+p-4+17)%17;
        if (i2<4||i2>12) continue;
        for (int q=0;q<9;++q){
            int j2=(w+q-4+17)%17;
            if (j2<4||j2>12) continue;
            int al=(12-i2)*9+(12-j2);
            int be=(8-p)*9+(8-q);
            acc += PP[al*81+be];
        }
    }
    pi[t]=acc;
}

// |FFT2(pi zero-padded to 128x128)|^2 max. 256 blocks x 64 thr (1 wave).
__global__ __launch_bounds__(64) void k_dft(const float* __restrict__ pi, float* __restrict__ scalars)
{
    __shared__ float spi[289], ct[128], st[128];
    int tid=threadIdx.x; int gid=blockIdx.x*64+tid;
    for (int e=tid; e<289; e+=64) spi[e]=pi[e];
    for (int e=tid; e<128; e+=64){ float ang=(float)e*(6.28318530717958647692f/128.f);
                  ct[e]=cosf(ang); st[e]=sinf(ang); }
    __syncthreads();
    int u=gid>>7, v=gid&127;
    float re=0.f, im=0.f;
    for (int i=0;i<17;++i){
        int ku=(u*i)&127;
        const float* prow=spi+i*17;
        for (int j=0;j<17;++j){
            int k=(ku+v*j)&127;
            float x=prow[j];
            re=fmaf(x,ct[k],re); im=fmaf(x,st[k],im);
        }
    }
    float m2=re*re+im*im;
    #pragma unroll
    for (int d=32; d; d>>=1) m2=fmaxf(m2, __shfl_down(m2,d));
    if (tid==0) atomicMax(((unsigned*)scalars)+SC_LPK2, __float_as_uint(m2));
}

// per-atom: center, subtract af@gram, row-normalize. Writes af_rn AND af_rnT.
__global__ __launch_bounds__(128) void k_atoms1(const float* __restrict__ atoms_in,
    const float* __restrict__ gram, float* __restrict__ af_rn, float* __restrict__ af_rnT)
{
    int a=blockIdx.x, tid=threadIdx.x;
    __shared__ float a0[81], a1[81], rbuf[128];
    float v = (tid<81)? atoms_in[a*81+tid] : 0.f;
    rbuf[tid]=v; __syncthreads();
    for (int off=64; off; off>>=1){ if (tid<off) rbuf[tid]+=rbuf[tid+off]; __syncthreads(); }
    float mean = rbuf[0]/81.f;
    __syncthreads();
    if (tid<81) a0[tid]=v-mean;
    __syncthreads();
    float w=0.f;
    if (tid<81){ float dot=0.f;
        for (int k=0;k<81;++k) dot=fmaf(a0[k], gram[k*81+tid], dot);
        w=a0[tid]-dot; a1[tid]=w; }
    rbuf[tid]=(tid<81)? w*w : 0.f;
    __syncthreads();
    for (int off=64; off; off>>=1){ if (tid<off) rbuf[tid]+=rbuf[tid+off]; __syncthreads(); }
    float inv = 1.f/sqrtf(rbuf[0]);
    if (tid<81){ float r=a1[tid]*inv; af_rn[a*81+tid]=r; af_rnT[tid*64+a]=r; }
}

// M = af_rn af_rn^T. 16 blocks x 256.
__global__ __launch_bounds__(256) void k_M(const float* __restrict__ af_rn,
    const float* __restrict__ af_rnT, float* __restrict__ M)
{
    int e=blockIdx.x*256+threadIdx.x;
    int i=e>>6, j=e&63;
    float a=0.f;
    for (int k=0;k<81;++k) a=fmaf(af_rn[i*81+k], af_rnT[(k<<6)+j], a);
    M[e]=a;
}

// k_fin: one block. A=M^2, power 48 on A, Rayleigh with M, finalize.
__global__ __launch_bounds__(256) void k_fin(const float* __restrict__ Mg,
    const float* __restrict__ af_rn, float* __restrict__ scalars,
    float* __restrict__ atoms_f, float* __restrict__ atomsT, float* __restrict__ Xmat)
{
    __shared__ __align__(16) float sM [64*68];
    __shared__ __align__(16) float sA [64*68];
    __shared__ float sGc[2];
    int tid=threadIdx.x;
    for (int e=tid; e<4096; e+=256) sM[(e>>6)*68+(e&63)]=Mg[e];
    for (int e=tid; e<64*68; e+=256){ if ((e%68)>=64) sM[e]=0.f; }
    __syncthreads();
    for (int e=tid; e<4096; e+=256){
        int i=e>>6, j=e&63;
        const float4* ri = reinterpret_cast<const float4*>(sM + i*68);
        const float4* rj = reinterpret_cast<const float4*>(sM + j*68);
        float a0=0.f,a1=0.f,a2=0.f,a3=0.f;
        #pragma unroll
        for (int k=0;k<16;++k){
            float4 x=ri[k], y=rj[k];
            a0=fmaf(x.x,y.x,a0); a1=fmaf(x.y,y.y,a1);
            a2=fmaf(x.z,y.z,a2); a3=fmaf(x.w,y.w,a3);
        }
        sA[i*68+j]=(a0+a1)+(a2+a3);
    }
    __syncthreads();
    if (tid<64){
        float m[64];
        #pragma unroll
        for (int j=0;j<64;++j) m[j]=sA[tid*68+j];
        float v = 1.0f + 0.01f*(float)tid;
        for (int it=0; it<48; ++it){
            float a0=0.f,a1=0.f,a2=0.f,a3=0.f;
            #pragma unroll
            for (int j=0;j<64;j+=4){
                a0=fmaf(m[j+0], __shfl(v,j+0), a0);
                a1=fmaf(m[j+1], __shfl(v,j+1), a1);
                a2=fmaf(m[j+2], __shfl(v,j+2), a2);
                a3=fmaf(m[j+3], __shfl(v,j+3), a3);
            }
            float nv=(a0+a1)+(a2+a3);
            float mx=fabsf(nv);
            #pragma unroll
            for (int d=1; d<64; d<<=1) mx=fmaxf(mx, __shfl_xor(mx,d));
            v=nv/mx;
        }
        float w0=0.f,w1=0.f,w2=0.f,w3=0.f;
        #pragma unroll
        for (int j=0;j<64;j+=4){
            w0=fmaf(sM[tid*68+j+0], __shfl(v,j+0), w0);
            w1=fmaf(sM[tid*68+j+1], __shfl(v,j+1), w1);
            w2=fmaf(sM[tid*68+j+2], __shfl(v,j+2), w2);
            w3=fmaf(sM[tid*68+j+3], __shfl(v,j+3), w3);
        }
        float wv=(w0+w1)+(w2+w3);
        float num=v*wv, den=v*v;
        #pragma unroll
        for (int d=1; d<64; d<<=1){ num+=__shfl_xor(num,d); den+=__shfl_xor(den,d); }
        if (tid==0){
            float sig = sqrtf(num/den);
            float b = scalars[SC_BETA];
            float s = sqrtf(0.99f/fmaxf(b,0.1f));
            float g = s/sig;
            scalars[SC_G]=g; scalars[SC_G2]=g*g;
            float lpk = sqrtf(__uint_as_float(((unsigned*)scalars)[SC_LPK2]));
            scalars[SC_L] = 1.01f*b*lpk;
            sGc[0]=g; sGc[1]=g*g;
        }
    }
    __syncthreads();
    float g=sGc[0], g2=sGc[1];
    for (int idx=tid; idx<5184; idx+=256){
        int a=idx/81, pq=idx-a*81;
        float v=g*af_rn[idx];
        atoms_f[idx]=v;
        atomsT[pq*64+a]=v;
    }
    for (int e=tid; e<4096; e+=256) Xmat[e]=g2*sM[(e>>6)*68+(e&63)];
}

// ---------------------------------------------------------------------------
// kA: coefficient update. grid (row-pair, batch), 512 threads, og halves
// merged (one c/nc HBM fetch per block). Round-8 proven form.
template<bool FIRST>
__global__ __launch_bounds__(512) void kA(const float* __restrict__ c_in,
    const float* __restrict__ nc_in, const float* __restrict__ nimg,
    const float* __restrict__ Xmat, const float* __restrict__ atomsT,
    const float* __restrict__ scalars, const float* __restrict__ lmbda_p,
    const float* __restrict__ red_in,
    float* __restrict__ c_out, float* __restrict__ nc_out, float mom)
{
    int b=blockIdx.y, rp=blockIdx.x;
    int tid=threadIdx.x;
    int og = tid>>8;
    int lid = tid&255;
    int ty=lid>>7, w=lid&127;
    int h0=rp*2;
    __shared__ float simg[10*128];
    __shared__ float sX[4096];
    __shared__ float sA[5184];
    __shared__ float sAct;
    if (FIRST){ if (tid==0) sAct=1.f; }
    else if (tid<64){
        float sd=red_in[(b<<7)+(tid<<1)], si=red_in[(b<<7)+(tid<<1)+1];
        #pragma unroll
        for (int off=32; off; off>>=1){ sd+=__shfl_down(sd,off); si+=__shfl_down(si,off); }
        if (tid==0) sAct = (sd > TOLV*TOLV*si) ? 1.f : 0.f;
    }
    for (int e=tid; e<1280; e+=512)
        simg[e]=nimg[b*NPIX + (((h0-4+(e>>7))&127)<<7) + (e&127)];
    if (!FIRST)
        for (int e=tid; e<4096; e+=512) sX[e]=Xmat[e];
    for (int e=tid; e<5184; e+=512) sA[e]=atomsT[e];
    __syncthreads();
    int pix=((h0+ty)<<7)+w;
    const float* cp  = c_in  + b*NCH*NPIX + pix;
    const float* ncp = nc_in + b*NCH*NPIX + pix;
    float acc[32];
    #pragma unroll
    for (int o=0;o<32;++o) acc[o]=0.f;
    if (!FIRST){
        for (int c=0;c<64;++c){
            float ncv=ncp[c*NPIX], cv=cp[c*NPIX];
            float t=fmaf(mom, ncv-cv, ncv);
            const float4* Xr = reinterpret_cast<const float4*>(sX + (c<<6) + (og<<5));
            #pragma unroll
            for (int i=0;i<8;++i){
                float4 x=Xr[i];
                acc[4*i+0]=fmaf(x.x,t,acc[4*i+0]);
                acc[4*i+1]=fmaf(x.y,t,acc[4*i+1]);
                acc[4*i+2]=fmaf(x.z,t,acc[4*i+2]);
                acc[4*i+3]=fmaf(x.w,t,acc[4*i+3]);
            }
        }
    }
    for (int p=0;p<9;++p){
        const float* srow = simg + (ty+p)*128;
        for (int q=0;q<9;++q){
            float wv = -srow[(w+q-4)&127];
            const float4* Ar = reinterpret_cast<const float4*>(sA + ((p*9+q)<<6) + (og<<5));
            #pragma unroll
            for (int i=0;i<8;++i){
                float4 x=Ar[i];
                acc[4*i+0]=fmaf(x.x,wv,acc[4*i+0]);
                acc[4*i+1]=fmaf(x.y,wv,acc[4*i+1]);
                acc[4*i+2]=fmaf(x.z,wv,acc[4*i+2]);
                acc[4*i+3]=fmaf(x.w,wv,acc[4*i+3]);
            }
        }
    }
    float beta=scalars[SC_BETA], lmb=lmbda_p[0];
    bool act = (sAct!=0.f);
    int co = og*32;
    const float* cpo  = cp  + co*NPIX;
    const float* ncpo = ncp + co*NPIX;
    float* cop  = c_out  + b*NCH*NPIX + co*NPIX + pix;
    float* ncop = nc_out + b*NCH*NPIX + co*NPIX + pix;
    #pragma unroll
    for (int o=0;o<32;++o){
        float ncv, cv, t;
        if (FIRST){ ncv=0.f; cv=0.f; t=0.f; }
        else { ncv=ncpo[o*NPIX]; cv=cpo[o*NPIX]; t=fmaf(mom, ncv-cv, ncv); }
        float u=fmaf(-beta, acc[o], t);
        float au=fabsf(u)-lmb;
        u = (au>0.f)? copysignf(au,u) : 0.f;
        ncop[o*NPIX] = act? u : ncv;
        cop[o*NPIX]  = act? ncv : cv;
    }
}

// kB1: dict_pred partials, CHANNEL-split. grid (16 rowblk, 16 cgroup, 4 b),
// 128 thr, 8 px/thread, 4 channels per cgroup. 1024 blocks x 2 waves =
// 8 waves/CU; per-(c,p) 4 float4 loads feed 72 fmas (18 fma/load).
__global__ __launch_bounds__(128) void kB1(const float* __restrict__ nc2,
    const float* __restrict__ atoms_f, float* __restrict__ part)
{
    int b=blockIdx.z, cg=blockIdx.y, pb=blockIdx.x;
    int t=threadIdx.x;
    int row = pb*8 + (t>>4);
    int cb  = (t&15)*8;
    const float* src = nc2 + (b*NCH + cg*4)*NPIX;
    float acc[8];
    #pragma unroll
    for (int k=0;k<8;++k) acc[k]=0.f;
    for (int c=0;c<4;++c){
        const float* chan = src + c*NPIX;
        const float* arow = atoms_f + (cg*4+c)*81;
        #pragma unroll 3
        for (int p=0;p<9;++p){
            int r=(row+4-p)&127;
            const float* rp_ = chan + (r<<7);
            float in16[16];
            #pragma unroll
            for (int k4=0;k4<4;++k4){
                int col=(cb-4+(k4<<2))&127;
                const float4 vv = *reinterpret_cast<const float4*>(rp_+col);
                in16[(k4<<2)+0]=vv.x; in16[(k4<<2)+1]=vv.y;
                in16[(k4<<2)+2]=vv.z; in16[(k4<<2)+3]=vv.w;
            }
            #pragma unroll
            for (int q=0;q<9;++q){
                float a = arow[p*9+q];
                #pragma unroll
                for (int k=0;k<8;++k) acc[k]=fmaf(in16[k+8-q], a, acc[k]);
            }
        }
    }
    float* dst = part + (cg*NB+b)*NPIX + (row<<7) + cb;
    #pragma unroll
    for (int k=0;k<8;++k) dst[k]=acc[k];
}

// kB2: image update + residual block partials (+ in-block active flag)
template<bool FIRST>
__global__ __launch_bounds__(256) void kB2(const float* __restrict__ img,
    const float* __restrict__ nimg, const float* __restrict__ y,
    const float* __restrict__ part, const float* __restrict__ pi,
    const float* __restrict__ scalars, const float* __restrict__ red_in,
    float* __restrict__ img_out, float* __restrict__ nimg_out,
    float* __restrict__ red_out, float mom)
{
    int b=blockIdx.y, rp=blockIdx.x;
    int tid=threadIdx.x, ty=tid>>7, w=tid&127;
    int h0=rp*2;
    __shared__ float sti[18*128];
    __shared__ float spi[289];
    __shared__ float rsd[4], rsi[4];
    __shared__ float sAct;
    if (FIRST){ if (tid==0) sAct=1.f; }
    else if (tid<64){
        float sd=red_in[(b<<7)+(tid<<1)], si=red_in[(b<<7)+(tid<<1)+1];
        #pragma unroll
        for (int off=32; off; off>>=1){ sd+=__shfl_down(sd,off); si+=__shfl_down(si,off); }
        if (tid==0) sAct = (sd > TOLV*TOLV*si) ? 1.f : 0.f;
    }
    const float* ib  = img  + b*NPIX;
    const float* nib = nimg + b*NPIX;
    for (int e=tid; e<2304; e+=256){
        int r=e>>7, cc=e&127;
        int idx=(((h0-8+r)&127)<<7)+cc;
        float nv=nib[idx], v=ib[idx];
        sti[e]=fmaf(mom, nv-v, nv);
    }
    for (int e=tid; e<289; e+=256) spi[e]=pi[e];
    __syncthreads();
    float sp=0.f;
    for (int p=0;p<17;++p){
        const float* srow = sti + (ty+p)*128;
        const float* pr = spi + p*17;
        #pragma unroll
        for (int q=0;q<17;++q) sp=fmaf(srow[(w+q-8)&127], pr[q], sp);
    }
    int pix=((h0+ty)<<7)+w;
    float dp=0.f;
    #pragma unroll
    for (int g=0; g<NPG; ++g) dp += part[(g*NB+b)*NPIX + pix];
    float ti = sti[(ty+8)*128 + w];
    float beta=scalars[SC_BETA], L=scalars[SC_L];
    float yv=y[b*NPIX+pix];
    float upd = ti - (ti - yv + beta*(sp - dp))/L;
    bool act = (sAct!=0.f);
    float iv=ib[pix], niv=nib[pix];
    float i2 = act? niv : iv;
    float ni2 = act? upd : niv;
    img_out[b*NPIX+pix]=i2;
    nimg_out[b*NPIX+pix]=ni2;
    float d=i2-ni2;
    float sd=d*d, si=i2*i2;
    #pragma unroll
    for (int off=32; off; off>>=1){ sd+=__shfl_down(sd,off); si+=__shfl_down(si,off); }
    if ((tid&63)==0){ rsd[tid>>6]=sd; rsi[tid>>6]=si; }
    __syncthreads();
    if (tid==0){
        float a=rsd[0]+rsd[1]+rsd[2]+rsd[3];
        float c2=rsi[0]+rsi[1]+rsi[2]+rsi[3];
        red_out[(b<<7)+(rp<<1)+0]=a;
        red_out[(b<<7)+(rp<<1)+1]=c2;
    }
}

// ---------------------------------------------------------------------------
extern "C" void kernel_launch(void* const* d_in, const int* in_sizes, int n_in,
                              void* d_out, int out_size, void* d_ws, size_t ws_size,
                              hipStream_t stream)
{
    const float* y        = (const float*)d_in[0];
    const float* atoms_p  = (const float*)d_in[1];
    const float* fatoms_p = (const float*)d_in[2];
    const float* beta_p   = (const float*)d_in[3];
    const float* lmbda_p  = (const float*)d_in[4];
    float* out = (float*)d_out;
    float* w = (float*)d_ws;

    size_t off=0;
    float* cb[2];  cb[0]=w+off;  off+=NCOEF; cb[1]=w+off;  off+=NCOEF;
    float* ncb[2]; ncb[0]=w+off; off+=NCOEF; ncb[1]=w+off; off+=NCOEF;
    float* ib[2];  ib[0]=w+off;  off+=NIMG;  ib[1]=w+off;  off+=NIMG;
    float* nib[2]; nib[0]=w+off; off+=NIMG;  nib[1]=w+off; off+=NIMG;
    float* part=w+off;    off+=NPG*NIMG;
    float* red[2]; red[0]=w+off; off+=512; red[1]=w+off; off+=512;
    float* gram=w+off;    off+=6561;
    float* pf=w+off;      off+=6561;
    float* PP=w+off;      off+=6561;
    float* pi=w+off;      off+=512;
    float* af_rn=w+off;   off+=5184;
    float* af_rnT=w+off;  off+=5184;
    float* Mmat=w+off;    off+=4096;
    float* atoms_f=w+off; off+=5184;
    float* atomsT=w+off;  off+=5184;
    float* Xmat=w+off;    off+=4096;
    float* scalars=w+off; off+=32;

    k_prep1<<<dim3(1),dim3(256),0,stream>>>(fatoms_p, beta_p, gram, pf, scalars);
    k_PP<<<dim3(26),dim3(256),0,stream>>>(pf, PP);
    k_impulse<<<dim3(1),dim3(320),0,stream>>>(PP, pi);
    k_dft<<<dim3(256),dim3(64),0,stream>>>(pi, scalars);
    k_atoms1<<<dim3(64),dim3(128),0,stream>>>(atoms_p, gram, af_rn, af_rnT);
    k_M<<<dim3(16),dim3(256),0,stream>>>(af_rn, af_rnT, Mmat);
    k_fin<<<dim3(1),dim3(256),0,stream>>>(Mmat, af_rn, scalars, atoms_f, atomsT, Xmat);

    int p=0;
    for (int k=1; k<=20; ++k){
        float mom = (float)(k-1)/(float)(k+2);
        const float* rin = red[(k-1)&1];
        float* rout = red[k&1];
        const float* img_i  = (k==1)? y : ib[p];
        const float* nimg_i = (k==1)? y : nib[p];
        float* nc_t  = (k==20)? (out+NIMG) : ncb[p^1];
        float* nimg_t= (k==20)? out : nib[p^1];
        if (k==1){
            kA<true><<<dim3(64,4),dim3(512),0,stream>>>(cb[p],ncb[p],nimg_i,Xmat,atomsT,
                scalars,lmbda_p,rin, cb[p^1],nc_t,mom);
        } else {
            kA<false><<<dim3(64,4),dim3(512),0,stream>>>(cb[p],ncb[p],nimg_i,Xmat,atomsT,
                scalars,lmbda_p,rin, cb[p^1],nc_t,mom);
        }
        kB1<<<dim3(16,16,4),dim3(128),0,stream>>>(nc_t, atoms_f, part);
        if (k==1){
            kB2<true><<<dim3(64,4),dim3(256),0,stream>>>(img_i,nimg_i,y,part,pi,scalars,rin,
                ib[p^1],nimg_t,rout,mom);
        } else {
            kB2<false><<<dim3(64,4),dim3(256),0,stream>>>(img_i,nimg_i,y,part,pi,scalars,rin,
                ib[p^1],nimg_t,rout,mom);
        }
        p^=1;
    }
}